// Round 2
// baseline (264.322 us; speedup 1.0000x reference)
//
#include <hip/hip_runtime.h>
#include <math.h>

// YOLO loss: pred/target (4096,14,14,30) fp32 -> scalar.
// Memory-bound reduction. Coalesced float4 staging into LDS (two-phase,
// single 30KB buffer to keep occupancy), per-cell compute from LDS.

#define SGRID 14
#define NCLS 20
#define CELLS_PER_BLOCK 256
#define F4_PER_BLOCK 1920   // 256 cells * 30 floats / 4

constexpr float STEPF  = 1.0f / 14.0f;
constexpr float EPSF   = 1e-7f;
constexpr float L_COORD = 5.0f;
constexpr float L_NOOBJ = 0.5f;

__device__ __forceinline__ float waveSum(float v) {
#pragma unroll
    for (int o = 32; o > 0; o >>= 1) v += __shfl_down(v, o);
    return v;
}

__global__ __launch_bounds__(256) void yolo_main(const float* __restrict__ pred,
                                                 const float* __restrict__ targ,
                                                 float* __restrict__ acc) {
    __shared__ float4 lds4[F4_PER_BLOCK];   // 30720 B
    const int t = threadIdx.x;

    // ---- Phase A: stage pred (coalesced), read this thread's cell to regs ----
    float pv[30];
    {
        const float4* src = reinterpret_cast<const float4*>(pred) + (size_t)blockIdx.x * F4_PER_BLOCK;
#pragma unroll
        for (int j = 0; j < 8; ++j) {
            int idx = j * 256 + t;
            if (idx < F4_PER_BLOCK) lds4[idx] = src[idx];
        }
    }
    __syncthreads();
    {
        const float2* c = reinterpret_cast<const float2*>(lds4) + t * 15;
#pragma unroll
        for (int j = 0; j < 15; ++j) { float2 v = c[j]; pv[2 * j] = v.x; pv[2 * j + 1] = v.y; }
    }
    __syncthreads();

    // ---- Phase B: stage targ into the same buffer, read to regs ----
    float tv[30];
    {
        const float4* src = reinterpret_cast<const float4*>(targ) + (size_t)blockIdx.x * F4_PER_BLOCK;
#pragma unroll
        for (int j = 0; j < 8; ++j) {
            int idx = j * 256 + t;
            if (idx < F4_PER_BLOCK) lds4[idx] = src[idx];
        }
    }
    __syncthreads();
    {
        const float2* c = reinterpret_cast<const float2*>(lds4) + t * 15;
#pragma unroll
        for (int j = 0; j < 15; ++j) { float2 v = c[j]; tv[2 * j] = v.x; tv[2 * j + 1] = v.y; }
    }

    // ---- Per-cell compute (identical math to verified R0 kernel) ----
    const float* p = pv;
    const float* tt = tv;
    int cell = blockIdx.x * CELLS_PER_BLOCK + t;     // layout (n, jy, ix)
    float ix = (float)(cell % SGRID);
    float jy = (float)((cell / SGRID) % SGRID);

    float s_obj = 0.f, s_noobj = 0.f, s_bbox = 0.f, s_nobj = 0.f, s_cls = 0.f, s_sm = 0.f;

    // paired IOU on cell-converted boxes (argmax only)
    float iouP[2];
#pragma unroll
    for (int b = 0; b < 2; ++b) {
        const float* pb = p + 5 * b;
        const float* tb = tt + 5 * b;
        float px = fmaxf((pb[0] + ix) * STEPF - pb[2] * 0.5f, 0.f);
        float py = fmaxf((pb[1] + jy) * STEPF - pb[3] * 0.5f, 0.f);
        float pw = fmaxf(pb[2], 0.f), ph = fmaxf(pb[3], 0.f);
        float tx = fmaxf((tb[0] + ix) * STEPF - tb[2] * 0.5f, 0.f);
        float ty = fmaxf((tb[1] + jy) * STEPF - tb[3] * 0.5f, 0.f);
        float tw = fmaxf(tb[2], 0.f), th = fmaxf(tb[3], 0.f);
        float iw = pw + tw - (fmaxf(px + pw, tx + tw) - fminf(px, tx));
        float ih = ph + th - (fmaxf(py + ph, ty + th) - fminf(py, ty));
        float inter = fmaxf(iw, 0.f) * fmaxf(ih, 0.f);
        float uni = pw * ph + tw * th - inter + EPSF;
        iouP[b] = inter / uni;
    }
    int maxi = (iouP[1] > iouP[0]) ? 1 : 0;   // jnp.argmax: ties -> 0
    bool sig = tt[9] > 0.f;                   // target box1 conf

#pragma unroll
    for (int b = 0; b < 2; ++b) {
        const float* pb = p + 5 * b;
        const float* tb = tt + 5 * b;
        bool om = tb[4] > 0.f;
        bool kp = (!sig) || (b == maxi);
        float f = (om && kp) ? 1.f : 0.f;

        float d = pb[4] - tb[4];
        float d2 = d * d;
        s_obj   += f * d2;
        s_noobj += (1.f - f) * d2;

        // DIoU on raw xywh -> xyxy
        float px1 = pb[0] - pb[2] * 0.5f, py1 = pb[1] - pb[3] * 0.5f;
        float px2 = pb[0] + pb[2] * 0.5f, py2 = pb[1] + pb[3] * 0.5f;
        float tx1 = tb[0] - tb[2] * 0.5f, ty1 = tb[1] - tb[3] * 0.5f;
        float tx2 = tb[0] + tb[2] * 0.5f, ty2 = tb[1] + tb[3] * 0.5f;

        float xi1 = fmaxf(px1, tx1), yi1 = fmaxf(py1, ty1);
        float xi2 = fminf(px2, tx2), yi2 = fminf(py2, ty2);
        float inter = fmaxf(xi2 - xi1, 0.f) * fmaxf(yi2 - yi1, 0.f);
        float a1 = fmaxf(px2 - px1, 0.f) * fmaxf(py2 - py1, 0.f);
        float a2 = fmaxf(tx2 - tx1, 0.f) * fmaxf(ty2 - ty1, 0.f);
        float iou = fmaxf(inter / (a1 + a2 - inter + EPSF), EPSF);

        float pcx = (px1 + px2) * 0.5f, pcy = (py1 + py2) * 0.5f;
        float tcx = (tx1 + tx2) * 0.5f, tcy = (ty1 + ty2) * 0.5f;
        float cd = (pcx - tcx) * (pcx - tcx) + (pcy - tcy) * (pcy - tcy);
        float ex1 = fminf(px1, tx1), ey1 = fminf(py1, ty1);
        float ex2 = fmaxf(px2, tx2), ey2 = fmaxf(py2, ty2);
        float diag = (ex2 - ex1) * (ex2 - ex1) + (ey2 - ey1) * (ey2 - ey1) + EPSF;
        float diou = 1.f - sqrtf(iou) + cd / diag;

        s_bbox += f * diou;
        s_nobj += f;
    }

    // focal class loss
    float fs = 0.f;
#pragma unroll
    for (int k = 0; k < NCLS; ++k) {
        float ce = p[10 + k] - tt[10 + k];
        ce *= ce;
        float pt = __expf(-ce);
        pt = fminf(fmaxf(pt, EPSF), 1.0f);
        float om1 = 1.f - pt;
        fs += om1 * om1 * ce;
    }
    float smv = sig ? 1.f : 0.f;
    s_cls += smv * fs;
    s_sm  += smv;

    // ---- reduce: wave shuffle -> LDS across 4 waves -> 6 atomics/block ----
    float r[6] = { s_obj, s_noobj, s_bbox, s_nobj, s_cls, s_sm };
#pragma unroll
    for (int q = 0; q < 6; ++q) r[q] = waveSum(r[q]);

    __shared__ float red[4][6];
    int lane = threadIdx.x & 63;
    int wv   = threadIdx.x >> 6;
    if (lane == 0) {
#pragma unroll
        for (int q = 0; q < 6; ++q) red[wv][q] = r[q];
    }
    __syncthreads();
    if (threadIdx.x == 0) {
#pragma unroll
        for (int q = 0; q < 6; ++q) {
            float a = red[0][q] + red[1][q] + red[2][q] + red[3][q];
            atomicAdd(&acc[q], a);
        }
    }
}

__global__ void yolo_final(const float* __restrict__ acc, float* __restrict__ out, float invN) {
    float obj   = acc[0];
    float noobj = acc[1];
    float bboxS = acc[2];
    float nObj  = acc[3];
    float clsS  = acc[4];
    float smS   = acc[5];

    float bbox_loss = (nObj > 0.f) ? (bboxS / fmaxf(nObj, 1.f)) : 0.f;
    float nCls = smS * (float)NCLS;
    float class_loss = (nCls > 0.f) ? (clsS / fmaxf(nCls, 1.f)) : 0.f;
    float total = obj + L_NOOBJ * noobj + L_COORD * bbox_loss + class_loss;
    out[0] = total * invN;
}

extern "C" void kernel_launch(void* const* d_in, const int* in_sizes, int n_in,
                              void* d_out, int out_size, void* d_ws, size_t ws_size,
                              hipStream_t stream) {
    const float* pred = (const float*)d_in[0];
    const float* targ = (const float*)d_in[1];
    float* out = (float*)d_out;
    float* acc = (float*)d_ws;

    int N = in_sizes[0] / (SGRID * SGRID * 30);       // 4096
    int totalCells = N * SGRID * SGRID;               // 802816 = 3136 * 256
    int blocks = totalCells / CELLS_PER_BLOCK;        // 3136, exact

    hipMemsetAsync(acc, 0, 6 * sizeof(float), stream);
    yolo_main<<<blocks, 256, 0, stream>>>(pred, targ, acc);
    yolo_final<<<1, 1, 0, stream>>>(acc, out, 1.0f / (float)N);
}

// Round 3
// 44.207 us; speedup vs baseline: 5.9792x; 5.9792x over previous
//
#include <hip/hip_runtime.h>
#include <math.h>

// YOLO loss: pred/target (4096,14,14,30) fp32 -> scalar.
// R2: no global atomics (per-block partials + reduce kernel); wave-private
// LDS staging (no barriers in hot path), coalesced float4 loads.

#define SGRID 14
#define NCLS 20
#define TILES_PER_WAVE 2
#define F4_PER_TILE 480          // 64 cells * 30 floats / 4

constexpr float STEPF  = 1.0f / 14.0f;
constexpr float EPSF   = 1e-7f;
constexpr float L_COORD = 5.0f;
constexpr float L_NOOBJ = 0.5f;

__device__ __forceinline__ float waveSum(float v) {
#pragma unroll
    for (int o = 32; o > 0; o >>= 1) v += __shfl_down(v, o);
    return v;
}

__global__ __launch_bounds__(256) void yolo_main(const float* __restrict__ pred,
                                                 const float* __restrict__ targ,
                                                 float* __restrict__ ws) {
    __shared__ float4 stage[4][F4_PER_TILE];   // 30720 B, wave-private chunks
    __shared__ float red[4][6];

    const int t = threadIdx.x;
    const int w = t >> 6;       // wave in block
    const int l = t & 63;       // lane

    float s[6] = {0.f, 0.f, 0.f, 0.f, 0.f, 0.f};  // obj, noobj, bbox, nobj, cls, sm

    const int gwave = blockIdx.x * 4 + w;
    float4* const dst = stage[w];

#pragma unroll
    for (int it = 0; it < TILES_PER_WAVE; ++it) {
        const int tile = gwave * TILES_PER_WAVE + it;   // 64 cells per tile

        // ---- stage pred (coalesced float4), read this lane's cell ----
        float pv[30], tv[30];
        {
            const float4* src = reinterpret_cast<const float4*>(pred) + (size_t)tile * F4_PER_TILE;
#pragma unroll
            for (int r = 0; r < 7; ++r) dst[r * 64 + l] = src[r * 64 + l];
            if (l < 32) dst[448 + l] = src[448 + l];
            const float2* c = reinterpret_cast<const float2*>(dst) + l * 15;
#pragma unroll
            for (int j = 0; j < 15; ++j) { float2 v = c[j]; pv[2 * j] = v.x; pv[2 * j + 1] = v.y; }
        }
        // ---- stage targ into same chunk (same-wave DS ordering, no barrier) ----
        {
            const float4* src = reinterpret_cast<const float4*>(targ) + (size_t)tile * F4_PER_TILE;
#pragma unroll
            for (int r = 0; r < 7; ++r) dst[r * 64 + l] = src[r * 64 + l];
            if (l < 32) dst[448 + l] = src[448 + l];
            const float2* c = reinterpret_cast<const float2*>(dst) + l * 15;
#pragma unroll
            for (int j = 0; j < 15; ++j) { float2 v = c[j]; tv[2 * j] = v.x; tv[2 * j + 1] = v.y; }
        }

        // ---- per-cell compute (math identical to verified R0/R1) ----
        const float* p = pv;
        const float* tt = tv;
        int cell = tile * 64 + l;                 // layout (n, jy, ix)
        float ix = (float)(cell % SGRID);
        float jy = (float)((cell / SGRID) % SGRID);

        float iouP[2];
#pragma unroll
        for (int b = 0; b < 2; ++b) {
            const float* pb = p + 5 * b;
            const float* tb = tt + 5 * b;
            float px = fmaxf((pb[0] + ix) * STEPF - pb[2] * 0.5f, 0.f);
            float py = fmaxf((pb[1] + jy) * STEPF - pb[3] * 0.5f, 0.f);
            float pw = fmaxf(pb[2], 0.f), ph = fmaxf(pb[3], 0.f);
            float tx = fmaxf((tb[0] + ix) * STEPF - tb[2] * 0.5f, 0.f);
            float ty = fmaxf((tb[1] + jy) * STEPF - tb[3] * 0.5f, 0.f);
            float tw = fmaxf(tb[2], 0.f), th = fmaxf(tb[3], 0.f);
            float iw = pw + tw - (fmaxf(px + pw, tx + tw) - fminf(px, tx));
            float ih = ph + th - (fmaxf(py + ph, ty + th) - fminf(py, ty));
            float inter = fmaxf(iw, 0.f) * fmaxf(ih, 0.f);
            float uni = pw * ph + tw * th - inter + EPSF;
            iouP[b] = inter / uni;
        }
        int maxi = (iouP[1] > iouP[0]) ? 1 : 0;   // jnp.argmax: ties -> 0
        bool sig = tt[9] > 0.f;

#pragma unroll
        for (int b = 0; b < 2; ++b) {
            const float* pb = p + 5 * b;
            const float* tb = tt + 5 * b;
            bool om = tb[4] > 0.f;
            bool kp = (!sig) || (b == maxi);
            float f = (om && kp) ? 1.f : 0.f;

            float d = pb[4] - tb[4];
            float d2 = d * d;
            s[0] += f * d2;
            s[1] += (1.f - f) * d2;

            float px1 = pb[0] - pb[2] * 0.5f, py1 = pb[1] - pb[3] * 0.5f;
            float px2 = pb[0] + pb[2] * 0.5f, py2 = pb[1] + pb[3] * 0.5f;
            float tx1 = tb[0] - tb[2] * 0.5f, ty1 = tb[1] - tb[3] * 0.5f;
            float tx2 = tb[0] + tb[2] * 0.5f, ty2 = tb[1] + tb[3] * 0.5f;

            float xi1 = fmaxf(px1, tx1), yi1 = fmaxf(py1, ty1);
            float xi2 = fminf(px2, tx2), yi2 = fminf(py2, ty2);
            float inter = fmaxf(xi2 - xi1, 0.f) * fmaxf(yi2 - yi1, 0.f);
            float a1 = fmaxf(px2 - px1, 0.f) * fmaxf(py2 - py1, 0.f);
            float a2 = fmaxf(tx2 - tx1, 0.f) * fmaxf(ty2 - ty1, 0.f);
            float iou = fmaxf(inter / (a1 + a2 - inter + EPSF), EPSF);

            float pcx = (px1 + px2) * 0.5f, pcy = (py1 + py2) * 0.5f;
            float tcx = (tx1 + tx2) * 0.5f, tcy = (ty1 + ty2) * 0.5f;
            float cd = (pcx - tcx) * (pcx - tcx) + (pcy - tcy) * (pcy - tcy);
            float ex1 = fminf(px1, tx1), ey1 = fminf(py1, ty1);
            float ex2 = fmaxf(px2, tx2), ey2 = fmaxf(py2, ty2);
            float diag = (ex2 - ex1) * (ex2 - ex1) + (ey2 - ey1) * (ey2 - ey1) + EPSF;
            float diou = 1.f - sqrtf(iou) + cd / diag;

            s[2] += f * diou;
            s[3] += f;
        }

        float fs = 0.f;
#pragma unroll
        for (int k = 0; k < NCLS; ++k) {
            float ce = p[10 + k] - tt[10 + k];
            ce *= ce;
            float pt = __expf(-ce);
            pt = fminf(fmaxf(pt, EPSF), 1.0f);
            float om1 = 1.f - pt;
            fs += om1 * om1 * ce;
        }
        float smv = sig ? 1.f : 0.f;
        s[4] += smv * fs;
        s[5] += smv;
    }

    // ---- reduce: wave shuffle -> LDS across 4 waves -> per-block store ----
#pragma unroll
    for (int q = 0; q < 6; ++q) s[q] = waveSum(s[q]);
    if (l == 0) {
#pragma unroll
        for (int q = 0; q < 6; ++q) red[w][q] = s[q];
    }
    __syncthreads();
    if (t == 0) {
        float4 o0, o1;
        float v[6];
#pragma unroll
        for (int q = 0; q < 6; ++q) v[q] = red[0][q] + red[1][q] + red[2][q] + red[3][q];
        o0 = make_float4(v[0], v[1], v[2], v[3]);
        o1 = make_float4(v[4], v[5], 0.f, 0.f);
        float4* o = reinterpret_cast<float4*>(ws + (size_t)blockIdx.x * 8);
        o[0] = o0;
        o[1] = o1;
    }
}

__global__ __launch_bounds__(256) void yolo_reduce(const float* __restrict__ ws,
                                                   float* __restrict__ out,
                                                   int nBlocks, float invN) {
    float s[6] = {0.f, 0.f, 0.f, 0.f, 0.f, 0.f};
    for (int row = threadIdx.x; row < nBlocks; row += 256) {
        const float4* r4 = reinterpret_cast<const float4*>(ws + (size_t)row * 8);
        float4 a = r4[0], b = r4[1];
        s[0] += a.x; s[1] += a.y; s[2] += a.z; s[3] += a.w; s[4] += b.x; s[5] += b.y;
    }
#pragma unroll
    for (int q = 0; q < 6; ++q) s[q] = waveSum(s[q]);

    __shared__ float red[4][6];
    int lane = threadIdx.x & 63;
    int wv   = threadIdx.x >> 6;
    if (lane == 0) {
#pragma unroll
        for (int q = 0; q < 6; ++q) red[wv][q] = s[q];
    }
    __syncthreads();
    if (threadIdx.x == 0) {
        float obj   = red[0][0] + red[1][0] + red[2][0] + red[3][0];
        float noobj = red[0][1] + red[1][1] + red[2][1] + red[3][1];
        float bboxS = red[0][2] + red[1][2] + red[2][2] + red[3][2];
        float nObj  = red[0][3] + red[1][3] + red[2][3] + red[3][3];
        float clsS  = red[0][4] + red[1][4] + red[2][4] + red[3][4];
        float smS   = red[0][5] + red[1][5] + red[2][5] + red[3][5];

        float bbox_loss = (nObj > 0.f) ? (bboxS / fmaxf(nObj, 1.f)) : 0.f;
        float nCls = smS * (float)NCLS;
        float class_loss = (nCls > 0.f) ? (clsS / fmaxf(nCls, 1.f)) : 0.f;
        float total = obj + L_NOOBJ * noobj + L_COORD * bbox_loss + class_loss;
        out[0] = total * invN;
    }
}

extern "C" void kernel_launch(void* const* d_in, const int* in_sizes, int n_in,
                              void* d_out, int out_size, void* d_ws, size_t ws_size,
                              hipStream_t stream) {
    const float* pred = (const float*)d_in[0];
    const float* targ = (const float*)d_in[1];
    float* out = (float*)d_out;
    float* ws = (float*)d_ws;

    int N = in_sizes[0] / (SGRID * SGRID * 30);       // 4096
    int totalCells = N * SGRID * SGRID;               // 802816
    int tiles = totalCells / 64;                      // 12544
    int gwaves = tiles / TILES_PER_WAVE;              // 6272
    int blocks = gwaves / 4;                          // 1568

    yolo_main<<<blocks, 256, 0, stream>>>(pred, targ, ws);
    yolo_reduce<<<1, 256, 0, stream>>>(ws, out, blocks, 1.0f / (float)N);
}

// Round 4
// 39.661 us; speedup vs baseline: 6.6645x; 1.1146x over previous
//
#include <hip/hip_runtime.h>
#include <math.h>

// YOLO loss: pred/target (4096,14,14,30) fp32 -> scalar.
// R3: global_load_lds (width 16) direct-to-LDS staging, pred+targ issued
// together -> ONE vmcnt(0) per tile; wave-private regions, no barriers in
// hot path, per-block partials + tiny reduce kernel (no global atomics).

#define SGRID 14
#define NCLS 20
#define TILES_PER_WAVE 2
#define F4_PER_TILE 480          // 64 cells * 30 floats / 4 (per input)

constexpr float STEPF  = 1.0f / 14.0f;
constexpr float EPSF   = 1e-7f;
constexpr float L_COORD = 5.0f;
constexpr float L_NOOBJ = 0.5f;

__device__ __forceinline__ float waveSum(float v) {
#pragma unroll
    for (int o = 32; o > 0; o >>= 1) v += __shfl_down(v, o);
    return v;
}

__device__ __forceinline__ void gload_lds16(const float4* gsrc, float4* ldst) {
    __builtin_amdgcn_global_load_lds(
        (const __attribute__((address_space(1))) void*)gsrc,
        (__attribute__((address_space(3))) void*)ldst, 16, 0, 0);
}

__global__ __launch_bounds__(256) void yolo_main(const float* __restrict__ pred,
                                                 const float* __restrict__ targ,
                                                 float* __restrict__ ws) {
    // 4 waves x 960 float4 = 61440 B. Layout per wave: [0..479]=pred tile,
    // [480..959]=targ tile; cell c at float-offset c*30 within each half.
    __shared__ float4 stage[4][2 * F4_PER_TILE];
    __shared__ float red[4][6];

    const int t = threadIdx.x;
    const int w = t >> 6;       // wave in block
    const int l = t & 63;       // lane

    float s[6] = {0.f, 0.f, 0.f, 0.f, 0.f, 0.f};  // obj, noobj, bbox, nobj, cls, sm

    const int gwave = blockIdx.x * 4 + w;
    float4* const wbuf = stage[w];

    const float4* pred4 = reinterpret_cast<const float4*>(pred);
    const float4* targ4 = reinterpret_cast<const float4*>(targ);

#pragma unroll
    for (int it = 0; it < TILES_PER_WAVE; ++it) {
        const int tile = gwave * TILES_PER_WAVE + it;   // 64 cells per tile

        // Drain pending ds_reads of the previous tile before overwriting the
        // region, and pin program order around the async staging.
        asm volatile("s_waitcnt lgkmcnt(0)" ::: "memory");
        __builtin_amdgcn_sched_barrier(0);

        // ---- issue ALL staging (pred+targ) as 15 full-wave lds-direct loads ----
        {
            const float4* psrc = pred4 + (size_t)tile * F4_PER_TILE;
            const float4* tsrc = targ4 + (size_t)tile * F4_PER_TILE;
#pragma unroll
            for (int i = 0; i < 15; ++i) {
                int g = i * 64 + l;
                const float4* src = (g < F4_PER_TILE) ? (psrc + g) : (tsrc + (g - F4_PER_TILE));
                gload_lds16(src, wbuf + i * 64);
            }
        }
        asm volatile("s_waitcnt vmcnt(0)" ::: "memory");
        __builtin_amdgcn_sched_barrier(0);

        // ---- read this lane's cell (30+30 floats) from LDS ----
        float pv[30], tv[30];
        {
            const float2* cp = reinterpret_cast<const float2*>(wbuf) + l * 15;
            const float2* ct = reinterpret_cast<const float2*>(wbuf + F4_PER_TILE) + l * 15;
#pragma unroll
            for (int j = 0; j < 15; ++j) {
                float2 a = cp[j]; pv[2 * j] = a.x; pv[2 * j + 1] = a.y;
                float2 b = ct[j]; tv[2 * j] = b.x; tv[2 * j + 1] = b.y;
            }
        }

        // ---- per-cell compute (math identical to verified R0-R2) ----
        const float* p = pv;
        const float* tt = tv;
        int cell = tile * 64 + l;                 // layout (n, jy, ix)
        float ix = (float)(cell % SGRID);
        float jy = (float)((cell / SGRID) % SGRID);

        float iouP[2];
#pragma unroll
        for (int b = 0; b < 2; ++b) {
            const float* pb = p + 5 * b;
            const float* tb = tt + 5 * b;
            float px = fmaxf((pb[0] + ix) * STEPF - pb[2] * 0.5f, 0.f);
            float py = fmaxf((pb[1] + jy) * STEPF - pb[3] * 0.5f, 0.f);
            float pw = fmaxf(pb[2], 0.f), ph = fmaxf(pb[3], 0.f);
            float tx = fmaxf((tb[0] + ix) * STEPF - tb[2] * 0.5f, 0.f);
            float ty = fmaxf((tb[1] + jy) * STEPF - tb[3] * 0.5f, 0.f);
            float tw = fmaxf(tb[2], 0.f), th = fmaxf(tb[3], 0.f);
            float iw = pw + tw - (fmaxf(px + pw, tx + tw) - fminf(px, tx));
            float ih = ph + th - (fmaxf(py + ph, ty + th) - fminf(py, ty));
            float inter = fmaxf(iw, 0.f) * fmaxf(ih, 0.f);
            float uni = pw * ph + tw * th - inter + EPSF;
            iouP[b] = inter / uni;
        }
        int maxi = (iouP[1] > iouP[0]) ? 1 : 0;   // jnp.argmax: ties -> 0
        bool sig = tt[9] > 0.f;

#pragma unroll
        for (int b = 0; b < 2; ++b) {
            const float* pb = p + 5 * b;
            const float* tb = tt + 5 * b;
            bool om = tb[4] > 0.f;
            bool kp = (!sig) || (b == maxi);
            float f = (om && kp) ? 1.f : 0.f;

            float d = pb[4] - tb[4];
            float d2 = d * d;
            s[0] += f * d2;
            s[1] += (1.f - f) * d2;

            float px1 = pb[0] - pb[2] * 0.5f, py1 = pb[1] - pb[3] * 0.5f;
            float px2 = pb[0] + pb[2] * 0.5f, py2 = pb[1] + pb[3] * 0.5f;
            float tx1 = tb[0] - tb[2] * 0.5f, ty1 = tb[1] - tb[3] * 0.5f;
            float tx2 = tb[0] + tb[2] * 0.5f, ty2 = tb[1] + tb[3] * 0.5f;

            float xi1 = fmaxf(px1, tx1), yi1 = fmaxf(py1, ty1);
            float xi2 = fminf(px2, tx2), yi2 = fminf(py2, ty2);
            float inter = fmaxf(xi2 - xi1, 0.f) * fmaxf(yi2 - yi1, 0.f);
            float a1 = fmaxf(px2 - px1, 0.f) * fmaxf(py2 - py1, 0.f);
            float a2 = fmaxf(tx2 - tx1, 0.f) * fmaxf(ty2 - ty1, 0.f);
            float iou = fmaxf(inter / (a1 + a2 - inter + EPSF), EPSF);

            float pcx = (px1 + px2) * 0.5f, pcy = (py1 + py2) * 0.5f;
            float tcx = (tx1 + tx2) * 0.5f, tcy = (ty1 + ty2) * 0.5f;
            float cd = (pcx - tcx) * (pcx - tcx) + (pcy - tcy) * (pcy - tcy);
            float ex1 = fminf(px1, tx1), ey1 = fminf(py1, ty1);
            float ex2 = fmaxf(px2, tx2), ey2 = fmaxf(py2, ty2);
            float diag = (ex2 - ex1) * (ex2 - ex1) + (ey2 - ey1) * (ey2 - ey1) + EPSF;
            float diou = 1.f - sqrtf(iou) + cd / diag;

            s[2] += f * diou;
            s[3] += f;
        }

        float fs = 0.f;
#pragma unroll
        for (int k = 0; k < NCLS; ++k) {
            float ce = p[10 + k] - tt[10 + k];
            ce *= ce;
            float pt = __expf(-ce);
            pt = fminf(fmaxf(pt, EPSF), 1.0f);
            float om1 = 1.f - pt;
            fs += om1 * om1 * ce;
        }
        float smv = sig ? 1.f : 0.f;
        s[4] += smv * fs;
        s[5] += smv;
    }

    // ---- reduce: wave shuffle -> LDS across 4 waves -> per-block store ----
#pragma unroll
    for (int q = 0; q < 6; ++q) s[q] = waveSum(s[q]);
    if (l == 0) {
#pragma unroll
        for (int q = 0; q < 6; ++q) red[w][q] = s[q];
    }
    __syncthreads();
    if (t == 0) {
        float v[6];
#pragma unroll
        for (int q = 0; q < 6; ++q) v[q] = red[0][q] + red[1][q] + red[2][q] + red[3][q];
        float4* o = reinterpret_cast<float4*>(ws + (size_t)blockIdx.x * 8);
        o[0] = make_float4(v[0], v[1], v[2], v[3]);
        o[1] = make_float4(v[4], v[5], 0.f, 0.f);
    }
}

__global__ __launch_bounds__(256) void yolo_reduce(const float* __restrict__ ws,
                                                   float* __restrict__ out,
                                                   int nBlocks, float invN) {
    float s[6] = {0.f, 0.f, 0.f, 0.f, 0.f, 0.f};
    for (int row = threadIdx.x; row < nBlocks; row += 256) {
        const float4* r4 = reinterpret_cast<const float4*>(ws + (size_t)row * 8);
        float4 a = r4[0], b = r4[1];
        s[0] += a.x; s[1] += a.y; s[2] += a.z; s[3] += a.w; s[4] += b.x; s[5] += b.y;
    }
#pragma unroll
    for (int q = 0; q < 6; ++q) s[q] = waveSum(s[q]);

    __shared__ float red[4][6];
    int lane = threadIdx.x & 63;
    int wv   = threadIdx.x >> 6;
    if (lane == 0) {
#pragma unroll
        for (int q = 0; q < 6; ++q) red[wv][q] = s[q];
    }
    __syncthreads();
    if (threadIdx.x == 0) {
        float obj   = red[0][0] + red[1][0] + red[2][0] + red[3][0];
        float noobj = red[0][1] + red[1][1] + red[2][1] + red[3][1];
        float bboxS = red[0][2] + red[1][2] + red[2][2] + red[3][2];
        float nObj  = red[0][3] + red[1][3] + red[2][3] + red[3][3];
        float clsS  = red[0][4] + red[1][4] + red[2][4] + red[3][4];
        float smS   = red[0][5] + red[1][5] + red[2][5] + red[3][5];

        float bbox_loss = (nObj > 0.f) ? (bboxS / fmaxf(nObj, 1.f)) : 0.f;
        float nCls = smS * (float)NCLS;
        float class_loss = (nCls > 0.f) ? (clsS / fmaxf(nCls, 1.f)) : 0.f;
        float total = obj + L_NOOBJ * noobj + L_COORD * bbox_loss + class_loss;
        out[0] = total * invN;
    }
}

extern "C" void kernel_launch(void* const* d_in, const int* in_sizes, int n_in,
                              void* d_out, int out_size, void* d_ws, size_t ws_size,
                              hipStream_t stream) {
    const float* pred = (const float*)d_in[0];
    const float* targ = (const float*)d_in[1];
    float* out = (float*)d_out;
    float* ws = (float*)d_ws;

    int N = in_sizes[0] / (SGRID * SGRID * 30);       // 4096
    int totalCells = N * SGRID * SGRID;               // 802816
    int tiles = totalCells / 64;                      // 12544
    int gwaves = tiles / TILES_PER_WAVE;              // 6272
    int blocks = gwaves / 4;                          // 1568

    yolo_main<<<blocks, 256, 0, stream>>>(pred, targ, ws);
    yolo_reduce<<<1, 256, 0, stream>>>(ws, out, blocks, 1.0f / (float)N);
}

// Round 5
// 39.119 us; speedup vs baseline: 6.7568x; 1.0138x over previous
//
#include <hip/hip_runtime.h>
#include <math.h>

// YOLO loss: pred/target (4096,14,14,30) fp32 -> scalar.
// R4: per-wave DOUBLE-BUFFERED global_load_lds staging with counted vmcnt
// (prefetch tile t+1 while computing tile t; memory pipe never drains).
// 128-thread blocks (2 waves), 60KB LDS, grid-stride over tiles.

#define SGRID 14
#define NCLS 20
#define F4_PER_TILE 480          // 64 cells * 30 floats / 4 (per input)
#define NT_TILES 12544           // 802816 cells / 64

constexpr float STEPF  = 1.0f / 14.0f;
constexpr float EPSF   = 1e-7f;
constexpr float L_COORD = 5.0f;
constexpr float L_NOOBJ = 0.5f;

__device__ __forceinline__ float waveSum(float v) {
#pragma unroll
    for (int o = 32; o > 0; o >>= 1) v += __shfl_down(v, o);
    return v;
}

__device__ __forceinline__ void gload_lds16(const float4* gsrc, float4* ldst) {
    __builtin_amdgcn_global_load_lds(
        (const __attribute__((address_space(1))) void*)gsrc,
        (__attribute__((address_space(3))) void*)ldst, 16, 0, 0);
}

// Issue one tile's staging: 15 full-wave direct-to-LDS loads (pred 480 f4,
// then targ 480 f4, contiguous in the wave's buffer).
__device__ __forceinline__ void issueTile(const float4* pred4, const float4* targ4,
                                          int tile, int l, float4* dst) {
    const float4* psrc = pred4 + (size_t)tile * F4_PER_TILE;
    const float4* tsrc = targ4 + (size_t)tile * F4_PER_TILE;
#pragma unroll
    for (int i = 0; i < 15; ++i) {
        int g = i * 64 + l;
        const float4* src = (g < F4_PER_TILE) ? (psrc + g) : (tsrc + (g - F4_PER_TILE));
        gload_lds16(src, dst + i * 64);
    }
}

__global__ __launch_bounds__(128) void yolo_main(const float* __restrict__ pred,
                                                 const float* __restrict__ targ,
                                                 float* __restrict__ ws) {
    // [wave][buf][960 float4] = 2*2*960*16 = 61440 B
    __shared__ float4 stage[2][2][2 * F4_PER_TILE];
    __shared__ float red[2][6];

    const int t = threadIdx.x;
    const int w = t >> 6;       // wave in block (0..1)
    const int l = t & 63;       // lane

    float s[6] = {0.f, 0.f, 0.f, 0.f, 0.f, 0.f};  // obj, noobj, bbox, nobj, cls, sm

    const int G = gridDim.x * 2;              // total gwaves
    const int gwave = blockIdx.x * 2 + w;

    const float4* pred4 = reinterpret_cast<const float4*>(pred);
    const float4* targ4 = reinterpret_cast<const float4*>(targ);

    int buf = 0;
    if (gwave < NT_TILES) issueTile(pred4, targ4, gwave, l, stage[w][0]);

    for (int tile = gwave; tile < NT_TILES; tile += G) {
        const int nxt = tile + G;

        // Prefetch next tile into the other buffer (its ds_reads finished one
        // iteration ago; drain lgkm defensively, then pin order).
        if (nxt < NT_TILES) {
            asm volatile("s_waitcnt lgkmcnt(0)" ::: "memory");
            __builtin_amdgcn_sched_barrier(0);
            issueTile(pred4, targ4, nxt, l, stage[w][buf ^ 1]);
            // Wait only for the OLDER 15 loads (current tile); the 15 newest
            // (next tile) stay in flight under this tile's compute.
            asm volatile("s_waitcnt vmcnt(15)" ::: "memory");
        } else {
            asm volatile("s_waitcnt vmcnt(0)" ::: "memory");
        }
        __builtin_amdgcn_sched_barrier(0);

        const float4* wbuf = stage[w][buf];
        buf ^= 1;

        // ---- read this lane's cell (30+30 floats) from LDS ----
        float pv[30], tv[30];
        {
            const float2* cp = reinterpret_cast<const float2*>(wbuf) + l * 15;
            const float2* ct = reinterpret_cast<const float2*>(wbuf + F4_PER_TILE) + l * 15;
#pragma unroll
            for (int j = 0; j < 15; ++j) {
                float2 a = cp[j]; pv[2 * j] = a.x; pv[2 * j + 1] = a.y;
                float2 b = ct[j]; tv[2 * j] = b.x; tv[2 * j + 1] = b.y;
            }
        }

        // ---- per-cell compute (math identical to verified R0-R3) ----
        const float* p = pv;
        const float* tt = tv;
        int cell = tile * 64 + l;                 // layout (n, jy, ix)
        float ix = (float)(cell % SGRID);
        float jy = (float)((cell / SGRID) % SGRID);

        float iouP[2];
#pragma unroll
        for (int b = 0; b < 2; ++b) {
            const float* pb = p + 5 * b;
            const float* tb = tt + 5 * b;
            float px = fmaxf((pb[0] + ix) * STEPF - pb[2] * 0.5f, 0.f);
            float py = fmaxf((pb[1] + jy) * STEPF - pb[3] * 0.5f, 0.f);
            float pw = fmaxf(pb[2], 0.f), ph = fmaxf(pb[3], 0.f);
            float tx = fmaxf((tb[0] + ix) * STEPF - tb[2] * 0.5f, 0.f);
            float ty = fmaxf((tb[1] + jy) * STEPF - tb[3] * 0.5f, 0.f);
            float tw = fmaxf(tb[2], 0.f), th = fmaxf(tb[3], 0.f);
            float iw = pw + tw - (fmaxf(px + pw, tx + tw) - fminf(px, tx));
            float ih = ph + th - (fmaxf(py + ph, ty + th) - fminf(py, ty));
            float inter = fmaxf(iw, 0.f) * fmaxf(ih, 0.f);
            float uni = pw * ph + tw * th - inter + EPSF;
            iouP[b] = inter / uni;
        }
        int maxi = (iouP[1] > iouP[0]) ? 1 : 0;   // jnp.argmax: ties -> 0
        bool sig = tt[9] > 0.f;

#pragma unroll
        for (int b = 0; b < 2; ++b) {
            const float* pb = p + 5 * b;
            const float* tb = tt + 5 * b;
            bool om = tb[4] > 0.f;
            bool kp = (!sig) || (b == maxi);
            float f = (om && kp) ? 1.f : 0.f;

            float d = pb[4] - tb[4];
            float d2 = d * d;
            s[0] += f * d2;
            s[1] += (1.f - f) * d2;

            float px1 = pb[0] - pb[2] * 0.5f, py1 = pb[1] - pb[3] * 0.5f;
            float px2 = pb[0] + pb[2] * 0.5f, py2 = pb[1] + pb[3] * 0.5f;
            float tx1 = tb[0] - tb[2] * 0.5f, ty1 = tb[1] - tb[3] * 0.5f;
            float tx2 = tb[0] + tb[2] * 0.5f, ty2 = tb[1] + tb[3] * 0.5f;

            float xi1 = fmaxf(px1, tx1), yi1 = fmaxf(py1, ty1);
            float xi2 = fminf(px2, tx2), yi2 = fminf(py2, ty2);
            float inter = fmaxf(xi2 - xi1, 0.f) * fmaxf(yi2 - yi1, 0.f);
            float a1 = fmaxf(px2 - px1, 0.f) * fmaxf(py2 - py1, 0.f);
            float a2 = fmaxf(tx2 - tx1, 0.f) * fmaxf(ty2 - ty1, 0.f);
            float iou = fmaxf(inter / (a1 + a2 - inter + EPSF), EPSF);

            float pcx = (px1 + px2) * 0.5f, pcy = (py1 + py2) * 0.5f;
            float tcx = (tx1 + tx2) * 0.5f, tcy = (ty1 + ty2) * 0.5f;
            float cd = (pcx - tcx) * (pcx - tcx) + (pcy - tcy) * (pcy - tcy);
            float ex1 = fminf(px1, tx1), ey1 = fminf(py1, ty1);
            float ex2 = fmaxf(px2, tx2), ey2 = fmaxf(py2, ty2);
            float diag = (ex2 - ex1) * (ex2 - ex1) + (ey2 - ey1) * (ey2 - ey1) + EPSF;
            float diou = 1.f - sqrtf(iou) + cd / diag;

            s[2] += f * diou;
            s[3] += f;
        }

        float fs = 0.f;
#pragma unroll
        for (int k = 0; k < NCLS; ++k) {
            float ce = p[10 + k] - tt[10 + k];
            ce *= ce;
            float pt = __expf(-ce);
            pt = fminf(fmaxf(pt, EPSF), 1.0f);
            float om1 = 1.f - pt;
            fs += om1 * om1 * ce;
        }
        float smv = sig ? 1.f : 0.f;
        s[4] += smv * fs;
        s[5] += smv;
    }

    // ---- reduce: wave shuffle -> LDS across 2 waves -> per-block store ----
#pragma unroll
    for (int q = 0; q < 6; ++q) s[q] = waveSum(s[q]);
    if (l == 0) {
#pragma unroll
        for (int q = 0; q < 6; ++q) red[w][q] = s[q];
    }
    __syncthreads();
    if (t == 0) {
        float v[6];
#pragma unroll
        for (int q = 0; q < 6; ++q) v[q] = red[0][q] + red[1][q];
        float4* o = reinterpret_cast<float4*>(ws + (size_t)blockIdx.x * 8);
        o[0] = make_float4(v[0], v[1], v[2], v[3]);
        o[1] = make_float4(v[4], v[5], 0.f, 0.f);
    }
}

__global__ __launch_bounds__(256) void yolo_reduce(const float* __restrict__ ws,
                                                   float* __restrict__ out,
                                                   int nBlocks, float invN) {
    float s[6] = {0.f, 0.f, 0.f, 0.f, 0.f, 0.f};
    for (int row = threadIdx.x; row < nBlocks; row += 256) {
        const float4* r4 = reinterpret_cast<const float4*>(ws + (size_t)row * 8);
        float4 a = r4[0], b = r4[1];
        s[0] += a.x; s[1] += a.y; s[2] += a.z; s[3] += a.w; s[4] += b.x; s[5] += b.y;
    }
#pragma unroll
    for (int q = 0; q < 6; ++q) s[q] = waveSum(s[q]);

    __shared__ float red[4][6];
    int lane = threadIdx.x & 63;
    int wv   = threadIdx.x >> 6;
    if (lane == 0) {
#pragma unroll
        for (int q = 0; q < 6; ++q) red[wv][q] = s[q];
    }
    __syncthreads();
    if (threadIdx.x == 0) {
        float obj   = red[0][0] + red[1][0] + red[2][0] + red[3][0];
        float noobj = red[0][1] + red[1][1] + red[2][1] + red[3][1];
        float bboxS = red[0][2] + red[1][2] + red[2][2] + red[3][2];
        float nObj  = red[0][3] + red[1][3] + red[2][3] + red[3][3];
        float clsS  = red[0][4] + red[1][4] + red[2][4] + red[3][4];
        float smS   = red[0][5] + red[1][5] + red[2][5] + red[3][5];

        float bbox_loss = (nObj > 0.f) ? (bboxS / fmaxf(nObj, 1.f)) : 0.f;
        float nCls = smS * (float)NCLS;
        float class_loss = (nCls > 0.f) ? (clsS / fmaxf(nCls, 1.f)) : 0.f;
        float total = obj + L_NOOBJ * noobj + L_COORD * bbox_loss + class_loss;
        out[0] = total * invN;
    }
}

extern "C" void kernel_launch(void* const* d_in, const int* in_sizes, int n_in,
                              void* d_out, int out_size, void* d_ws, size_t ws_size,
                              hipStream_t stream) {
    const float* pred = (const float*)d_in[0];
    const float* targ = (const float*)d_in[1];
    float* out = (float*)d_out;
    float* ws = (float*)d_ws;

    int N = in_sizes[0] / (SGRID * SGRID * 30);       // 4096
    (void)N;
    int blocks = 512;                                 // 2 per CU (60KB LDS each)

    yolo_main<<<blocks, 128, 0, stream>>>(pred, targ, ws);
    yolo_reduce<<<1, 256, 0, stream>>>(ws, out, blocks, 1.0f / 4096.0f);
}

// Round 6
// 38.001 us; speedup vs baseline: 6.9556x; 1.0294x over previous
//
#include <hip/hip_runtime.h>
#include <math.h>

// YOLO loss: pred/target (4096,14,14,30) fp32 -> scalar.
// R5: 32-cell tiles, 2 lanes per cell (box-split + class-split), per-wave
// double-buffered global_load_lds with counted vmcnt, 4-wave blocks,
// 61.5KB LDS -> 2 blocks/CU = 8 waves/CU sustained in-flight.

#define SGRID 14
#define NCLS 20
#define CELLS_PER_TILE 32
#define F4_PER_INPUT 240         // 32 cells * 30 floats / 4
#define TILE_F4 480              // both inputs
#define NT_TILES 25088           // 802816 cells / 32

constexpr float STEPF  = 1.0f / 14.0f;
constexpr float EPSF   = 1e-7f;
constexpr float L_COORD = 5.0f;
constexpr float L_NOOBJ = 0.5f;

__device__ __forceinline__ float waveSum(float v) {
#pragma unroll
    for (int o = 32; o > 0; o >>= 1) v += __shfl_down(v, o);
    return v;
}

__device__ __forceinline__ void gload_lds16(const void* gsrc, void* ldst) {
    __builtin_amdgcn_global_load_lds(
        (const __attribute__((address_space(1))) void*)gsrc,
        (__attribute__((address_space(3))) void*)ldst, 16, 0, 0);
}
__device__ __forceinline__ void gload_lds4(const void* gsrc, void* ldst) {
    __builtin_amdgcn_global_load_lds(
        (const __attribute__((address_space(1))) void*)gsrc,
        (__attribute__((address_space(3))) void*)ldst, 4, 0, 0);
}

// Stage one 32-cell tile (pred 240 f4 then targ 240 f4, contiguous floats
// [0..959]=pred, [960..1919]=targ): 7 wave-loads of 16B + 2 wave-loads of 4B.
__device__ __forceinline__ void issueTile(const float4* pred4, const float4* targ4,
                                          int tile, int l, float4* dst) {
    const float4* psrc = pred4 + (size_t)tile * F4_PER_INPUT;
    const float4* tsrc = targ4 + (size_t)tile * F4_PER_INPUT;
#pragma unroll
    for (int i = 0; i < 7; ++i) {
        int g = i * 64 + l;
        const float4* src = (g < F4_PER_INPUT) ? (psrc + g) : (tsrc + (g - F4_PER_INPUT));
        gload_lds16(src, dst + i * 64);
    }
    // tail: targ floats 832..959 -> buffer floats 1792..1919
    const float* tf = reinterpret_cast<const float*>(tsrc);
    float* df = reinterpret_cast<float*>(dst);
#pragma unroll
    for (int j = 0; j < 2; ++j) {
        gload_lds4(tf + 832 + j * 64 + l, df + 1792 + j * 64);
    }
}

__global__ __launch_bounds__(256, 2) void yolo_main(const float* __restrict__ pred,
                                                    const float* __restrict__ targ,
                                                    float* __restrict__ ws) {
    __shared__ float4 stage[4][2][TILE_F4];   // 61440 B
    __shared__ float red[4][6];

    const int t = threadIdx.x;
    const int w = t >> 6;       // wave in block (0..3)
    const int l = t & 63;       // lane
    const int c = l >> 1;       // cell within tile (0..31)
    const int b = l & 1;        // box index this lane owns

    float s0 = 0.f, s1 = 0.f, s2 = 0.f, s3 = 0.f, s4 = 0.f, s5 = 0.f;

    const int G = gridDim.x * 4;
    const int gwave = blockIdx.x * 4 + w;

    const float4* pred4 = reinterpret_cast<const float4*>(pred);
    const float4* targ4 = reinterpret_cast<const float4*>(targ);

    int buf = 0;
    if (gwave < NT_TILES) issueTile(pred4, targ4, gwave, l, stage[w][0]);

    for (int tile = gwave; tile < NT_TILES; tile += G) {
        const int nxt = tile + G;
        if (nxt < NT_TILES) {
            asm volatile("s_waitcnt lgkmcnt(0)" ::: "memory");
            __builtin_amdgcn_sched_barrier(0);
            issueTile(pred4, targ4, nxt, l, stage[w][buf ^ 1]);
            // wait only for current tile's 9 loads; next tile's 9 stay in flight
            asm volatile("s_waitcnt vmcnt(9)" ::: "memory");
        } else {
            asm volatile("s_waitcnt vmcnt(0)" ::: "memory");
        }
        __builtin_amdgcn_sched_barrier(0);

        const float* P = reinterpret_cast<const float*>(stage[w][buf]);
        const float* T = P + 960;
        buf ^= 1;

        // ---- box phase: lane owns box b of cell c ----
        const float2* p2 = reinterpret_cast<const float2*>(P + 30 * c);  // byte 120c, 8-aligned
        const float2* t2 = reinterpret_cast<const float2*>(T + 30 * c);
        float2 pA = p2[2 * b], pB = p2[2 * b + 1], pC = p2[2 * b + 2];
        float2 tA = t2[2 * b], tB = t2[2 * b + 1], tC = t2[2 * b + 2];
        float t9v = (T + 30 * c)[9];
        // floats 4b..4b+5 loaded; box floats are [b .. b+4] of those six
        float p0 = b ? pA.y : pA.x;
        float p1 = b ? pB.x : pA.y;
        float p2f = b ? pB.y : pB.x;
        float p3f = b ? pC.x : pB.y;
        float p4f = b ? pC.y : pC.x;
        float t0 = b ? tA.y : tA.x;
        float t1 = b ? tB.x : tA.y;
        float t2f = b ? tB.y : tB.x;
        float t3f = b ? tC.x : tB.y;
        float t4f = b ? tC.y : tC.x;

        int cell = tile * CELLS_PER_TILE + c;     // layout (n, jy, ix)
        float ix = (float)(cell % SGRID);
        float jy = (float)((cell / SGRID) % SGRID);

        // paired IOU (cell-converted) for argmax
        float px = fmaxf((p0 + ix) * STEPF - p2f * 0.5f, 0.f);
        float py = fmaxf((p1 + jy) * STEPF - p3f * 0.5f, 0.f);
        float pw = fmaxf(p2f, 0.f), ph = fmaxf(p3f, 0.f);
        float tx = fmaxf((t0 + ix) * STEPF - t2f * 0.5f, 0.f);
        float ty = fmaxf((t1 + jy) * STEPF - t3f * 0.5f, 0.f);
        float tw = fmaxf(t2f, 0.f), th = fmaxf(t3f, 0.f);
        float iw = pw + tw - (fmaxf(px + pw, tx + tw) - fminf(px, tx));
        float ih = ph + th - (fmaxf(py + ph, ty + th) - fminf(py, ty));
        float inter0 = fmaxf(iw, 0.f) * fmaxf(ih, 0.f);
        float iouP = inter0 / (pw * ph + tw * th - inter0 + EPSF);

        float other = __shfl_xor(iouP, 1);
        float i0 = b ? other : iouP;
        float i1 = b ? iouP : other;
        int maxi = (i1 > i0) ? 1 : 0;             // jnp.argmax: ties -> 0
        bool sig = t9v > 0.f;
        bool om = t4f > 0.f;
        bool kp = (!sig) || (b == maxi);
        float f = (om && kp) ? 1.f : 0.f;

        float d = p4f - t4f;
        float d2 = d * d;
        s0 += f * d2;
        s1 += (1.f - f) * d2;

        // DIoU on raw xywh -> xyxy
        float px1 = p0 - p2f * 0.5f, py1 = p1 - p3f * 0.5f;
        float px2 = p0 + p2f * 0.5f, py2 = p1 + p3f * 0.5f;
        float tx1 = t0 - t2f * 0.5f, ty1 = t1 - t3f * 0.5f;
        float tx2 = t0 + t2f * 0.5f, ty2 = t1 + t3f * 0.5f;

        float xi1 = fmaxf(px1, tx1), yi1 = fmaxf(py1, ty1);
        float xi2 = fminf(px2, tx2), yi2 = fminf(py2, ty2);
        float inter = fmaxf(xi2 - xi1, 0.f) * fmaxf(yi2 - yi1, 0.f);
        float a1 = fmaxf(px2 - px1, 0.f) * fmaxf(py2 - py1, 0.f);
        float a2 = fmaxf(tx2 - tx1, 0.f) * fmaxf(ty2 - ty1, 0.f);
        float iou = fmaxf(inter / (a1 + a2 - inter + EPSF), EPSF);

        float pcx = (px1 + px2) * 0.5f, pcy = (py1 + py2) * 0.5f;
        float tcx = (tx1 + tx2) * 0.5f, tcy = (ty1 + ty2) * 0.5f;
        float cd = (pcx - tcx) * (pcx - tcx) + (pcy - tcy) * (pcy - tcy);
        float ex1 = fminf(px1, tx1), ey1 = fminf(py1, ty1);
        float ex2 = fmaxf(px2, tx2), ey2 = fmaxf(py2, ty2);
        float diag = (ex2 - ex1) * (ex2 - ex1) + (ey2 - ey1) * (ey2 - ey1) + EPSF;
        float diou = 1.f - sqrtf(iou) + cd / diag;

        s2 += f * diou;
        s3 += f;

        // ---- class phase: lane handles 10 channels (10b..10b+9) of cell c ----
        const float2* pc2 = reinterpret_cast<const float2*>(P + 30 * c + 10 + 10 * b);
        const float2* tc2 = reinterpret_cast<const float2*>(T + 30 * c + 10 + 10 * b);
        float fs = 0.f;
#pragma unroll
        for (int m = 0; m < 5; ++m) {
            float2 a = pc2[m], e = tc2[m];
            float ce1 = a.x - e.x; ce1 *= ce1;
            float pt1 = fminf(fmaxf(__expf(-ce1), EPSF), 1.0f);
            float o1 = 1.f - pt1;
            fs += o1 * o1 * ce1;
            float ce2 = a.y - e.y; ce2 *= ce2;
            float pt2 = fminf(fmaxf(__expf(-ce2), EPSF), 1.0f);
            float o2 = 1.f - pt2;
            fs += o2 * o2 * ce2;
        }
        if (sig) {
            s4 += fs;
            if (b == 0) s5 += 1.f;
        }
    }

    // ---- reduce: wave shuffle -> LDS across 4 waves -> per-block store ----
    float s[6] = { s0, s1, s2, s3, s4, s5 };
#pragma unroll
    for (int q = 0; q < 6; ++q) s[q] = waveSum(s[q]);
    if (l == 0) {
#pragma unroll
        for (int q = 0; q < 6; ++q) red[w][q] = s[q];
    }
    __syncthreads();
    if (t == 0) {
        float v[6];
#pragma unroll
        for (int q = 0; q < 6; ++q) v[q] = red[0][q] + red[1][q] + red[2][q] + red[3][q];
        float4* o = reinterpret_cast<float4*>(ws + (size_t)blockIdx.x * 8);
        o[0] = make_float4(v[0], v[1], v[2], v[3]);
        o[1] = make_float4(v[4], v[5], 0.f, 0.f);
    }
}

__global__ __launch_bounds__(256) void yolo_reduce(const float* __restrict__ ws,
                                                   float* __restrict__ out,
                                                   int nBlocks, float invN) {
    float s[6] = {0.f, 0.f, 0.f, 0.f, 0.f, 0.f};
    for (int row = threadIdx.x; row < nBlocks; row += 256) {
        const float4* r4 = reinterpret_cast<const float4*>(ws + (size_t)row * 8);
        float4 a = r4[0], bq = r4[1];
        s[0] += a.x; s[1] += a.y; s[2] += a.z; s[3] += a.w; s[4] += bq.x; s[5] += bq.y;
    }
#pragma unroll
    for (int q = 0; q < 6; ++q) s[q] = waveSum(s[q]);

    __shared__ float red[4][6];
    int lane = threadIdx.x & 63;
    int wv   = threadIdx.x >> 6;
    if (lane == 0) {
#pragma unroll
        for (int q = 0; q < 6; ++q) red[wv][q] = s[q];
    }
    __syncthreads();
    if (threadIdx.x == 0) {
        float obj   = red[0][0] + red[1][0] + red[2][0] + red[3][0];
        float noobj = red[0][1] + red[1][1] + red[2][1] + red[3][1];
        float bboxS = red[0][2] + red[1][2] + red[2][2] + red[3][2];
        float nObj  = red[0][3] + red[1][3] + red[2][3] + red[3][3];
        float clsS  = red[0][4] + red[1][4] + red[2][4] + red[3][4];
        float smS   = red[0][5] + red[1][5] + red[2][5] + red[3][5];

        float bbox_loss = (nObj > 0.f) ? (bboxS / fmaxf(nObj, 1.f)) : 0.f;
        float nCls = smS * (float)NCLS;
        float class_loss = (nCls > 0.f) ? (clsS / fmaxf(nCls, 1.f)) : 0.f;
        float total = obj + L_NOOBJ * noobj + L_COORD * bbox_loss + class_loss;
        out[0] = total * invN;
    }
}

extern "C" void kernel_launch(void* const* d_in, const int* in_sizes, int n_in,
                              void* d_out, int out_size, void* d_ws, size_t ws_size,
                              hipStream_t stream) {
    const float* pred = (const float*)d_in[0];
    const float* targ = (const float*)d_in[1];
    float* out = (float*)d_out;
    float* ws = (float*)d_ws;

    int blocks = 512;   // 4 waves each, 61.5KB LDS -> 2 blocks/CU = 8 waves/CU

    yolo_main<<<blocks, 256, 0, stream>>>(pred, targ, ws);
    yolo_reduce<<<1, 256, 0, stream>>>(ws, out, blocks, 1.0f / 4096.0f);
}